// Round 4
// baseline (503.342 us; speedup 1.0000x reference)
//
#include <hip/hip_runtime.h>
#include <hip/hip_bf16.h>

#define HIDDEN 1024
#define INTER 4096
#define NEXP 8
#define T_TOK 2048

typedef short bf16x8 __attribute__((ext_vector_type(8)));
typedef float f32x4 __attribute__((ext_vector_type(4)));

__device__ __forceinline__ unsigned short f2bf(float f) {
    union { float f; unsigned int u; } v; v.f = f;
    unsigned int u = v.u;
    unsigned int r = (u + 0x7FFFu + ((u >> 16) & 1u)) >> 16;
    return (unsigned short)r;
}

// truncating fp32->bf16 pack of 4 floats -> 2 dwords (2x v_perm_b32)
__device__ __forceinline__ uint2 pack4trunc(float4 v) {
    union { float4 f; unsigned short s[8]; } u; u.f = v;
    uint2 r;
    r.x = (unsigned int)u.s[1] | ((unsigned int)u.s[3] << 16);
    r.y = (unsigned int)u.s[5] | ((unsigned int)u.s[7] << 16);
    return r;
}

// R2-proven zero-conflict layout: rows of 64 bf16 (128B), XOR bank swizzle.
__device__ __forceinline__ unsigned int swz(unsigned int row, unsigned int colByte) {
    return (row * 128u + colByte) ^ ((row & 7u) << 4);
}

// raw barrier: NO vmcnt drain (global prefetch stays in flight across it).
__device__ __forceinline__ void block_sync() {
    asm volatile("s_waitcnt lgkmcnt(0)" ::: "memory");
    __builtin_amdgcn_s_barrier();
    asm volatile("" ::: "memory");
}

// ---------------- K1: router (fp32 exact) ----------------
__global__ void router_kernel(const float* __restrict__ x,
                              const float* __restrict__ rw,
                              float* __restrict__ logits_out,
                              int* __restrict__ counts,
                              int* __restrict__ ids,
                              float* __restrict__ wts) {
    int t = blockIdx.x * 4 + (threadIdx.x >> 6);
    int lane = threadIdx.x & 63;
    if (t >= T_TOK) return;
    const float4* xr = (const float4*)(x + (size_t)t * HIDDEN);
    float acc[NEXP];
#pragma unroll
    for (int e = 0; e < NEXP; e++) acc[e] = 0.f;
#pragma unroll
    for (int c = 0; c < 4; c++) {
        float4 xv = xr[lane + c * 64];
#pragma unroll
        for (int e = 0; e < NEXP; e++) {
            float4 wv = ((const float4*)(rw + (size_t)e * HIDDEN))[lane + c * 64];
            acc[e] += xv.x * wv.x + xv.y * wv.y + xv.z * wv.z + xv.w * wv.w;
        }
    }
#pragma unroll
    for (int e = 0; e < NEXP; e++) {
        float v = acc[e];
        for (int off = 32; off >= 1; off >>= 1) v += __shfl_xor(v, off, 64);
        acc[e] = v;
    }
    if (lane == 0) {
        float* lo = logits_out + (size_t)t * NEXP;
        float mx = acc[0];
#pragma unroll
        for (int e = 1; e < NEXP; e++) mx = fmaxf(mx, acc[e]);
        float p[NEXP], s = 0.f;
#pragma unroll
        for (int e = 0; e < NEXP; e++) { p[e] = __expf(acc[e] - mx); s += p[e]; }
        float inv = 1.f / s;
#pragma unroll
        for (int e = 0; e < NEXP; e++) { p[e] *= inv; lo[e] = acc[e]; }
        int i1 = 0;
#pragma unroll
        for (int e = 1; e < NEXP; e++) if (p[e] > p[i1]) i1 = e;
        int i2 = (i1 == 0) ? 1 : 0;
#pragma unroll
        for (int e = 0; e < NEXP; e++) if (e != i1 && e != i2 && p[e] > p[i2]) i2 = e;
        int s1 = atomicAdd(&counts[i1], 1);
        ids[i1 * T_TOK + s1] = t; wts[i1 * T_TOK + s1] = p[i1];
        int s2 = atomicAdd(&counts[i2], 1);
        ids[i2 * T_TOK + s2] = t; wts[i2 * T_TOK + s2] = p[i2];
    }
}

__global__ void scan_kernel(const int* __restrict__ counts, int* __restrict__ offsets) {
    if (threadIdx.x == 0) {
        int s = 0;
        for (int e = 0; e < NEXP; e++) { offsets[e] = s; s += counts[e]; }
    }
}

// ---------------- K2: fused gate+up grouped GEMM + SwiGLU ----------------
// BM=256 x BN=64, BK=64, 512 thr (8 waves 4x2, wave-tile 64x32).
// LDS/buf: A 32KB | Bg 8KB | Bu 8KB = 48KB; dbuf = 96KB. Raw-barrier pipeline.
__global__ __launch_bounds__(512) void gemm_gu(
    const float* __restrict__ x, const float* __restrict__ gw, const float* __restrict__ uw,
    const int* __restrict__ counts, const int* __restrict__ offsets,
    const int* __restrict__ ids, unsigned short* __restrict__ h) {
    const int e = blockIdx.z;
    const int cnt = counts[e];
    const int mt = blockIdx.y;
    if (mt * 256 >= cnt) return;
    const int nt = blockIdx.x;                    // 64 tiles of 64 inter cols
    const int tid = threadIdx.x;
    const int lane = tid & 63, wid = tid >> 6;
    const int wm = wid >> 1, wn = wid & 1;        // 4x2 waves

    __shared__ __align__(16) char lds[98304];

    const float* gbase = gw + (size_t)e * INTER * HIDDEN;
    const float* ubase = uw + (size_t)e * INTER * HIDDEN;

    // A staging: 256 rows x 64 K fp32 = 4096 float4; 8 per thread
    unsigned int aoff[8], wA[8];
#pragma unroll
    for (int j = 0; j < 8; j++) {
        int fi = j * 512 + tid;
        int row = fi >> 4, c4 = fi & 15;
        int li = mt * 256 + row; if (li >= cnt) li = cnt - 1;
        int gid = ids[e * T_TOK + li];
        aoff[j] = (unsigned int)(gid * HIDDEN + c4 * 4);
        wA[j] = swz(row, c4 * 8);
    }
    // B staging: 64 rows x 64 K fp32 = 1024 float4; 2 per thread (x2 for g,u)
    unsigned int boff[2], wB[2];
#pragma unroll
    for (int j = 0; j < 2; j++) {
        int fi = j * 512 + tid;
        int row = fi >> 4, c4 = fi & 15;
        boff[j] = (unsigned int)((nt * 64 + row) * HIDDEN + c4 * 4);
        wB[j] = swz(row, c4 * 8);
    }

    f32x4 accg[4][2], accu[4][2];
#pragma unroll
    for (int mf = 0; mf < 4; mf++)
#pragma unroll
        for (int nf = 0; nf < 2; nf++)
#pragma unroll
            for (int v = 0; v < 4; v++) { accg[mf][nf][v] = 0.f; accu[mf][nf][v] = 0.f; }

    float4 av[8], gv[2], uv[2];
#pragma unroll
    for (int j = 0; j < 8; j++) av[j] = *(const float4*)(x + aoff[j]);
#pragma unroll
    for (int j = 0; j < 2; j++) {
        gv[j] = *(const float4*)(gbase + boff[j]);
        uv[j] = *(const float4*)(ubase + boff[j]);
    }

    for (int kt = 0; kt < 16; kt++) {
        const unsigned int bb = (unsigned int)(kt & 1) * 49152u;
#pragma unroll
        for (int j = 0; j < 8; j++) *(uint2*)(lds + bb + wA[j]) = pack4trunc(av[j]);
#pragma unroll
        for (int j = 0; j < 2; j++) {
            *(uint2*)(lds + bb + 32768 + wB[j]) = pack4trunc(gv[j]);
            *(uint2*)(lds + bb + 40960 + wB[j]) = pack4trunc(uv[j]);
        }
        if (kt < 15) {                            // prefetch next K-tile
            const int ko = (kt + 1) * 64;
#pragma unroll
            for (int j = 0; j < 8; j++) av[j] = *(const float4*)(x + aoff[j] + ko);
#pragma unroll
            for (int j = 0; j < 2; j++) {
                gv[j] = *(const float4*)(gbase + boff[j] + ko);
                uv[j] = *(const float4*)(ubase + boff[j] + ko);
            }
        }
        block_sync();
#pragma unroll
        for (int ks = 0; ks < 2; ks++) {
            const unsigned int kb = (unsigned int)(ks * 64 + ((lane >> 4) << 4));
            bf16x8 a[4], bg[2], bu[2];
#pragma unroll
            for (int mf = 0; mf < 4; mf++) {
                unsigned int row = (unsigned int)(wm * 64 + mf * 16 + (lane & 15));
                a[mf] = *(const bf16x8*)(lds + bb + swz(row, kb));
            }
#pragma unroll
            for (int nf = 0; nf < 2; nf++) {
                unsigned int row = (unsigned int)(wn * 32 + nf * 16 + (lane & 15));
                bg[nf] = *(const bf16x8*)(lds + bb + 32768 + swz(row, kb));
                bu[nf] = *(const bf16x8*)(lds + bb + 40960 + swz(row, kb));
            }
#pragma unroll
            for (int mf = 0; mf < 4; mf++)
#pragma unroll
                for (int nf = 0; nf < 2; nf++) {
                    accg[mf][nf] = __builtin_amdgcn_mfma_f32_16x16x32_bf16(a[mf], bg[nf], accg[mf][nf], 0, 0, 0);
                    accu[mf][nf] = __builtin_amdgcn_mfma_f32_16x16x32_bf16(a[mf], bu[nf], accu[mf][nf], 0, 0, 0);
                }
        }
    }

    const int hoff = offsets[e];
#pragma unroll
    for (int mf = 0; mf < 4; mf++)
#pragma unroll
        for (int v = 0; v < 4; v++) {
            int il = wm * 64 + mf * 16 + ((lane >> 4) << 2) + v;
            int i = mt * 256 + il;
            if (i < cnt) {
                size_t rowbase = (size_t)(hoff + i) * INTER + nt * 64 + wn * 32 + (lane & 15);
#pragma unroll
                for (int nf = 0; nf < 2; nf++) {
                    float g = accg[mf][nf][v], u = accu[mf][nf][v];
                    float sg = g / (1.f + __expf(-g));
                    h[rowbase + nf * 16] = f2bf(sg * u);
                }
            }
        }
}

// ---------------- K3: down grouped GEMM + weighted scatter-add ----------------
// BM=256 x BN=64, BK=64, ksplit=2, 512 thr (8 waves 4x2, wave-tile 64x32).
// LDS/buf: A 32KB | B 8KB = 40KB; dbuf = 80KB -> 2 blocks/CU.
__global__ __launch_bounds__(512) void gemm_down(
    const unsigned short* __restrict__ h, const float* __restrict__ dw,
    const int* __restrict__ counts, const int* __restrict__ offsets,
    const int* __restrict__ ids, const float* __restrict__ wts,
    float* __restrict__ out) {
    const int ez = blockIdx.z;                    // e*2 + ksplit
    const int e = ez >> 1, ksp = ez & 1;
    const int cnt = counts[e];
    const int mt = blockIdx.y;
    if (mt * 256 >= cnt) return;
    const int nt = blockIdx.x;                    // 16 tiles of 64 hidden cols
    const int tid = threadIdx.x;
    const int lane = tid & 63, wid = tid >> 6;
    const int wm = wid >> 1, wn = wid & 1;

    __shared__ __align__(16) char lds[81920];

    const int hoff = offsets[e];
    const float* dbase = dw + (size_t)e * HIDDEN * INTER;

    // A staging (h, bf16): 256 rows x 64 K = 2048 int4 chunks; 4 per thread
    unsigned int aoff[4], wA[4];
#pragma unroll
    for (int j = 0; j < 4; j++) {
        int fi = j * 512 + tid;
        int row = fi >> 3, c8 = fi & 7;
        int li = mt * 256 + row; if (li >= cnt) li = cnt - 1;
        aoff[j] = (unsigned int)((hoff + li) * INTER + ksp * 2048 + c8 * 8);
        wA[j] = swz(row, c8 * 16);
    }
    // B staging (dw, fp32): 64 rows x 64 K = 1024 float4; 2 per thread
    unsigned int boff[2], wB[2];
#pragma unroll
    for (int j = 0; j < 2; j++) {
        int fi = j * 512 + tid;
        int row = fi >> 4, c4 = fi & 15;
        boff[j] = (unsigned int)((nt * 64 + row) * INTER + ksp * 2048 + c4 * 4);
        wB[j] = swz(row, c4 * 8);
    }

    f32x4 acc[4][2];
#pragma unroll
    for (int mf = 0; mf < 4; mf++)
#pragma unroll
        for (int nf = 0; nf < 2; nf++)
#pragma unroll
            for (int v = 0; v < 4; v++) acc[mf][nf][v] = 0.f;

    int4 av[4]; float4 bv[2];
#pragma unroll
    for (int j = 0; j < 4; j++) av[j] = *(const int4*)(h + aoff[j]);
#pragma unroll
    for (int j = 0; j < 2; j++) bv[j] = *(const float4*)(dbase + boff[j]);

    for (int kt = 0; kt < 32; kt++) {
        const unsigned int bb = (unsigned int)(kt & 1) * 40960u;
#pragma unroll
        for (int j = 0; j < 4; j++) *(int4*)(lds + bb + wA[j]) = av[j];
#pragma unroll
        for (int j = 0; j < 2; j++) *(uint2*)(lds + bb + 32768 + wB[j]) = pack4trunc(bv[j]);
        if (kt < 31) {
            const int ko = (kt + 1) * 64;
#pragma unroll
            for (int j = 0; j < 4; j++) av[j] = *(const int4*)(h + aoff[j] + ko);
#pragma unroll
            for (int j = 0; j < 2; j++) bv[j] = *(const float4*)(dbase + boff[j] + ko);
        }
        block_sync();
#pragma unroll
        for (int ks = 0; ks < 2; ks++) {
            const unsigned int kb = (unsigned int)(ks * 64 + ((lane >> 4) << 4));
            bf16x8 a[4], bf[2];
#pragma unroll
            for (int mf = 0; mf < 4; mf++) {
                unsigned int row = (unsigned int)(wm * 64 + mf * 16 + (lane & 15));
                a[mf] = *(const bf16x8*)(lds + bb + swz(row, kb));
            }
#pragma unroll
            for (int nf = 0; nf < 2; nf++) {
                unsigned int row = (unsigned int)(wn * 32 + nf * 16 + (lane & 15));
                bf[nf] = *(const bf16x8*)(lds + bb + 32768 + swz(row, kb));
            }
#pragma unroll
            for (int mf = 0; mf < 4; mf++)
#pragma unroll
                for (int nf = 0; nf < 2; nf++)
                    acc[mf][nf] = __builtin_amdgcn_mfma_f32_16x16x32_bf16(a[mf], bf[nf], acc[mf][nf], 0, 0, 0);
        }
    }

#pragma unroll
    for (int mf = 0; mf < 4; mf++)
#pragma unroll
        for (int v = 0; v < 4; v++) {
            int il = wm * 64 + mf * 16 + ((lane >> 4) << 2) + v;
            int i = mt * 256 + il;
            if (i < cnt) {
                int t = ids[e * T_TOK + i];
                float w = wts[e * T_TOK + i];
                float* orow = out + (size_t)t * HIDDEN + nt * 64 + wn * 32 + (lane & 15);
#pragma unroll
                for (int nf = 0; nf < 2; nf++)
                    atomicAdd(orow + nf * 16, w * acc[mf][nf][v]);
            }
        }
}

extern "C" void kernel_launch(void* const* d_in, const int* in_sizes, int n_in,
                              void* d_out, int out_size, void* d_ws, size_t ws_size,
                              hipStream_t stream) {
    const float* x  = (const float*)d_in[0];
    const float* rw = (const float*)d_in[1];
    const float* gw = (const float*)d_in[2];
    const float* uw = (const float*)d_in[3];
    const float* dw = (const float*)d_in[4];
    float* out = (float*)d_out;
    float* logits = out + (size_t)T_TOK * HIDDEN;

    int* counts  = (int*)d_ws;
    int* offsets = counts + 8;
    int* ids     = (int*)((char*)d_ws + 64);
    float* wts   = (float*)((char*)d_ws + 64 + 8 * T_TOK * 4);
    unsigned short* h = (unsigned short*)((char*)d_ws + 262144);

    hipMemsetAsync(out, 0, (size_t)T_TOK * HIDDEN * sizeof(float), stream);
    hipMemsetAsync(counts, 0, 8 * sizeof(int), stream);

    router_kernel<<<T_TOK / 4, 256, 0, stream>>>(x, rw, logits, counts, ids, wts);
    scan_kernel<<<1, 64, 0, stream>>>(counts, offsets);
    gemm_gu<<<dim3(INTER / 64, 8, NEXP), 512, 0, stream>>>(x, gw, uw, counts, offsets, ids, h);
    gemm_down<<<dim3(HIDDEN / 64, 8, NEXP * 2), 512, 0, stream>>>(h, dw, counts, offsets, ids, wts, out);
}